// Round 6
// baseline (126.774 us; speedup 1.0000x reference)
//
#include <hip/hip_runtime.h>

// LIF neuron bank: B=16, N=2048, T=1000. Sequential scan in T per neuron.
//
// R5: fully-coalesced pipeline with wave specialization (512 blocks x 192):
//   wave 0 (compute): never touches global memory. Reads u from LDS
//     (swizzled, conflict-free ds_read_b128), runs 32 LIF steps/chunk,
//     writes s/v float4 to LDS (same swizzle).
//   wave 1 (loader): global_load_lds dwordx4, 8 insts/chunk. Inst k loads
//     rows 8k..8k+7, 128B contiguous per row; per-lane GLOBAL address is
//     pre-swizzled (slot = tf ^ (row&7)) while the LDS dest stays linear
//     (gll writes base + lane*16). Runs 2 chunks ahead; counted
//     s_waitcnt vmcnt(8) per phase (loads-only queue, never drains stores).
//   wave 2 (storer): R4's coalesced pattern: inst k stores rows 8k..8k+7,
//     128B contiguous per row, from swizzled LDS (conflict-free reads).
// CHUNK=32 steps (NF4=8), TRIPLE-buffered u/s/v = 72 KB LDS -> 2 blocks/CU.
// One barrier per phase; 31 full chunks + 8-step tail (compact layout).
//
// FP discipline: reference does NOT contract mul+add into FMA; use
// __fmul_rn/__fadd_rn/__fsub_rn to stay bit-exact (R0-R4: absmax 0.0).

constexpr int B_ = 16;
constexpr int N_ = 2048;
constexpr int T_ = 1000;
constexpr int CHUNK = 32;                    // steps per full chunk
constexpr int NF4 = CHUNK / 4;               // 8 float4 per row per chunk
constexpr int NFULL = 31;                    // full chunks c=0..30
constexpr int TAIL_T0 = NFULL * CHUNK;       // 992
constexpr int TAIL_F4 = (T_ - TAIL_T0) / 4;  // 2 float4 per row

// LDS-ordering barrier (no vmcnt drain).
#define LDS_BARRIER()                                          \
    do {                                                       \
        asm volatile("s_waitcnt lgkmcnt(0)" ::: "memory");     \
        __builtin_amdgcn_s_barrier();                          \
        __builtin_amdgcn_sched_barrier(0);                     \
    } while (0)

__device__ __forceinline__ void gload_lds16(const float* g, void* lds) {
    __builtin_amdgcn_global_load_lds(
        (const __attribute__((address_space(1))) void*)g,
        (__attribute__((address_space(3))) void*)lds, 16, 0, 0);
}

__global__ __launch_bounds__(192) void lif_kernel(
    const float* __restrict__ u,          // (B, N, T)
    const float* __restrict__ theta_base, // (1, N, 1) -> N floats
    float* __restrict__ spikes,           // (B, N, T)
    float* __restrict__ vhist)            // (B, N, T)
{
    __shared__ float4 u_lds[3][64][NF4];   // [buf][row][slot]
    __shared__ float4 s_lds[3][64][NF4];
    __shared__ float4 v_lds[3][64][NF4];

    const int lane = threadIdx.x & 63;
    const int wid = threadIdx.x >> 6;
    const int blk0 = blockIdx.x * 64;      // first neuron of block

    if (wid == 0) {
        // ---------------- compute wave ----------------
        const float tb = theta_base[(blk0 + lane) & (N_ - 1)];
        const float c5 = __fmul_rn(tb, 0.005f);   // tb * (1-0.995) rounded
        float v = 0.0f, theta = tb, ref = 0.0f;
        const int sw = lane & 7;

        // 4 LIF steps on one float4 of input -> s4, v4
        auto step4 = [&](const float4 u4, float4& s4, float4& v4) {
            const float uin[4] = {u4.x, u4.y, u4.z, u4.w};
            float so[4], vo[4];
#pragma unroll
            for (int k = 0; k < 4; ++k) {
                // u_eff = u_t * (1 - (ref>0))
                const float ueff = (ref > 0.0f) ? 0.0f : uin[k];
                // v = 0.95*v + u_eff   (separate mul/add, no FMA)
                v = __fadd_rn(__fmul_rn(0.95f, v), ueff);
                // s = (v - theta >= 0)
                const float d = __fsub_rn(v, theta);
                const bool s = (d >= 0.0f);
                // v -= s*theta
                v = s ? __fsub_rn(v, theta) : v;
                // ref = max(ref-1,0); if (s) ref = 2
                ref = fmaxf(__fsub_rn(ref, 1.0f), 0.0f);
                ref = s ? 2.0f : ref;
                // theta = theta*0.995 + tb*0.005 + 0.35*s
                theta = __fadd_rn(__fmul_rn(theta, 0.995f), c5);
                theta = s ? __fadd_rn(theta, 0.35f) : theta;

                so[k] = s ? 1.0f : 0.0f;
                vo[k] = v;
            }
            s4 = make_float4(so[0], so[1], so[2], so[3]);
            v4 = make_float4(vo[0], vo[1], vo[2], vo[3]);
        };

        __builtin_amdgcn_s_barrier();              // B(-1): chunk0 ready
        int bu = 0;
#pragma unroll 1
        for (int c = 0; c < NFULL; ++c) {          // phases 0..30
            const float4* urow = &u_lds[bu][lane][0];
            float4* srow = &s_lds[bu][lane][0];
            float4* vrow = &v_lds[bu][lane][0];
#pragma unroll
            for (int tf = 0; tf < NF4; ++tf) {
                float4 s4, v4;
                step4(urow[tf ^ sw], s4, v4);
                srow[tf ^ sw] = s4;
                vrow[tf ^ sw] = v4;
            }
            LDS_BARRIER();
            bu = (bu == 2) ? 0 : bu + 1;
        }
        // phase 31: tail (8 steps), compact [64][TAIL_F4] layout in buf bu(=1)
        {
            const float4* ut = &u_lds[bu][0][0];
            float4* st = &s_lds[bu][0][0];
            float4* vt = &v_lds[bu][0][0];
#pragma unroll
            for (int tf = 0; tf < TAIL_F4; ++tf) {
                float4 s4, v4;
                step4(ut[TAIL_F4 * lane + tf], s4, v4);
                st[TAIL_F4 * lane + tf] = s4;
                vt[TAIL_F4 * lane + tf] = v4;
            }
            LDS_BARRIER();                         // B(31)
        }
    } else if (wid == 1) {
        // ---------------- loader wave ----------------
        const float* ub = u + (size_t)blk0 * T_;
        const int r0 = lane >> 3;        // row offset within group of 8
        const int sl = lane & 7;         // LDS slot this lane fills

        auto issue_full = [&](int cc, int buf) {
#pragma unroll
            for (int k = 0; k < 8; ++k) {
                const int r = 8 * k + r0;
                // pre-swizzled global source; LDS dest linear = base+lane*16
                const float* g =
                    ub + (size_t)r * T_ + CHUNK * cc + 4 * (sl ^ (r & 7));
                gload_lds16(g, &u_lds[buf][8 * k][0]);
            }
        };
        auto issue_tail = [&]() {        // buf 1, compact [64][2] layout
#pragma unroll
            for (int j = 0; j < 2; ++j) {
                const int r = 32 * j + (lane >> 1);
                const int tf = lane & 1;
                const float* g = ub + (size_t)r * T_ + TAIL_T0 + 4 * tf;
                gload_lds16(g, ((float4*)&u_lds[1][0][0]) + 64 * j);
            }
        };

        issue_full(0, 0);
        issue_full(1, 1);
        asm volatile("s_waitcnt vmcnt(8)" ::: "memory");  // chunk0 landed
        __builtin_amdgcn_sched_barrier(0);
        __builtin_amdgcn_s_barrier();              // B(-1)
#pragma unroll 1
        for (int c = 0; c < NFULL + 1; ++c) {      // phases 0..31
            if (c <= 28) {
                issue_full(c + 2, (c + 2) % 3);
                asm volatile("s_waitcnt vmcnt(8)" ::: "memory"); // c+1 landed
            } else if (c == 29) {
                issue_tail();
                asm volatile("s_waitcnt vmcnt(2)" ::: "memory"); // chunk30 landed
            } else if (c == 30) {
                asm volatile("s_waitcnt vmcnt(0)" ::: "memory"); // tail landed
            }
            __builtin_amdgcn_sched_barrier(0);
            __builtin_amdgcn_s_barrier();
            __builtin_amdgcn_sched_barrier(0);
        }
    } else {
        // ---------------- storer wave ----------------
        float* gs = spikes + (size_t)blk0 * T_;
        float* gv = vhist + (size_t)blk0 * T_;
        const int r0 = lane >> 3;
        const int tfp = lane & 7;

        __builtin_amdgcn_s_barrier();              // B(-1)
#pragma unroll 1
        for (int c = 0; c < NFULL + 1; ++c) {      // phases 0..31
            if (c >= 1) {
                const int cc = c - 1;
                const int buf = cc % 3;
                const int t0 = CHUNK * cc;
#pragma unroll
                for (int k = 0; k < 8; ++k) {
                    const int r = 8 * k + r0;
                    const float4 w = s_lds[buf][r][tfp ^ (r & 7)];
                    *(float4*)(gs + (size_t)r * T_ + t0 + 4 * tfp) = w;
                }
#pragma unroll
                for (int k = 0; k < 8; ++k) {
                    const int r = 8 * k + r0;
                    const float4 w = v_lds[buf][r][tfp ^ (r & 7)];
                    *(float4*)(gv + (size_t)r * T_ + t0 + 4 * tfp) = w;
                }
            }
            LDS_BARRIER();
        }
        // epilogue: tail (chunk 31, buf 1 compact); all barriers passed
        {
            const float4* st = &s_lds[1][0][0];
            const float4* vt = &v_lds[1][0][0];
#pragma unroll
            for (int j = 0; j < 2; ++j) {
                const int r = 32 * j + (lane >> 1);
                const int tf = lane & 1;
                *(float4*)(gs + (size_t)r * T_ + TAIL_T0 + 4 * tf) =
                    st[64 * j + lane];
                *(float4*)(gv + (size_t)r * T_ + TAIL_T0 + 4 * tf) =
                    vt[64 * j + lane];
            }
        }
    }
}

extern "C" void kernel_launch(void* const* d_in, const int* in_sizes, int n_in,
                              void* d_out, int out_size, void* d_ws, size_t ws_size,
                              hipStream_t stream) {
    const float* u = (const float*)d_in[0];           // (B,N,T)
    const float* theta_base = (const float*)d_in[1];  // (1,N,1)
    float* out = (float*)d_out;
    float* spikes = out;                               // first output
    float* vhist = out + (size_t)B_ * N_ * T_;         // second output

    const int grid = (B_ * N_) / 64;   // 512 blocks (64 neurons each)
    lif_kernel<<<grid, 192, 0, stream>>>(u, theta_base, spikes, vhist);
}